// Round 11
// baseline (254.446 us; speedup 1.0000x reference)
//
#include <hip/hip_runtime.h>
#include <hip/hip_bf16.h>

#define NIN    512
#define NEVAL  1536
#define NCOLS  2048
#define NOUT   256
#define OUT_BASE 1280
#define BK     64
#define NBLK   24        // NEVAL / BK
#define NROWS  16        // batch rows per WG
#define WDS    68        // Wd col stride (floats): 16B-aligned
#define ZSTR   68        // Zc row stride (floats)

typedef __attribute__((ext_vector_type(8))) short short8;   // 8 bf16 (4 VGPRs)
typedef __attribute__((ext_vector_type(4))) float floatx4;  // MFMA C/D

#define C5 (-7.21347520444481703f)   // -5*log2(e): sigmoid(5z) = rcp(1+exp2(C5*z))

// ---------- helpers ----------

__device__ __forceinline__ unsigned short f2bf(float f) {
    __hip_bfloat16 h = __float2bfloat16(f);
    return __builtin_bit_cast(unsigned short, h);
}
__device__ __forceinline__ unsigned pack2(float a, float b) {
    return (unsigned)f2bf(a) | ((unsigned)f2bf(b) << 16);
}
// sigmoid in folded domain: y = C5*(z+b); sigma = rcp(1+exp2(y)). Overflow exact.
__device__ __forceinline__ float sig2(float y) {
    return __builtin_amdgcn_rcpf(1.0f + __builtin_amdgcn_exp2f(y));
}

// ---------- W fp32 -> bf16 (d_ws re-poisoned every launch, so rerun) ----------
// Workspace usage is EXACTLY NEVAL*NCOLS*2 bytes (proven safe).

__global__ __launch_bounds__(256) void wconv(const float* __restrict__ W,
                                             ushort* __restrict__ Wb, int n8) {
    int i = blockIdx.x * blockDim.x + threadIdx.x;
    if (i < n8) {
        float4 v0 = ((const float4*)W)[2 * i];
        float4 v1 = ((const float4*)W)[2 * i + 1];
        uint4 pk;
        pk.x = pack2(v0.x, v0.y); pk.y = pack2(v0.z, v0.w);
        pk.z = pack2(v1.x, v1.y); pk.w = pack2(v1.z, v1.w);
        ((uint4*)Wb)[i] = pk;
    }
}

// ---------- main kernel ----------
// ROUND-23 (= R22, macro-capture fixed: CLEAF's parameter renamed B->BOF;
// it was capturing the slot-name argument "B" in CSTEP -> wb00).
// Theory (R22): chain serialized on just-in-time weight ds_read_b128
// latency (~290 cyc/step; R20->R21 broadcast swap proved broadcast isn't
// the path). Two named register slots (A/B, 16 VGPR each); step J consumes
// slot[J&1] then issues loads for J+2 into the same slot. Loads fly across
// 2 compute steps; compiler's fine-grained lgkmcnt waits only on the older
// group (m97-verified). Mains' MFMA unroll 4->2 for register relief.
// Abort signal: WRITE_SIZE > 5MB = spill returned.
//   role 0      (1 wave): chain, lane=4r+g (row r's 4 node-groups in one
//               DPP quad). Per literal step J: sig2 local elem, quad_perm
//               broadcast from quad-lane J>>4, 16 unguarded fma (ride-along
//               weights exactly 0.0 from strict lower-tri W).
//   roles 1,2,3,5 (4 waves): mains, node-group ng. Phase 1: tail(k) = 2
//               MFMAs (B prefetched) + Zc^T store. Phase 2: main(k+1) over
//               [0,512+64k) into regs + prefetch tail B(k+1).
//   roles 4,6,7 (3 waves): stagers: Wd[(k+1)&1][j*WDS+i] = C5*W[...].
// Slot: phase1 | beta | phase2 | alpha. Disjoint: mains read O cols
// [0,512+64k); chain writes [512+64k,+64).

// --- chain macros: literal indices only ---
#define QP(g) ((g) | ((g) << 2) | ((g) << 4) | ((g) << 6))
#define CLOAD(J, S) { \
    const float* wl_ = wd + (J) * WDS + g16; \
    wb##S##0 = *(const floatx4*)(wl_); \
    wb##S##1 = *(const floatx4*)(wl_ + 4); \
    wb##S##2 = *(const floatx4*)(wl_ + 8); \
    wb##S##3 = *(const floatx4*)(wl_ + 12); \
}
#define CSTEP(J, Q, C, ON, S) { \
    float sg_ = sig2(vq##Q.C); \
    ON = __builtin_bit_cast(float, \
        __builtin_amdgcn_update_dpp(0, __builtin_bit_cast(int, sg_), \
                                    QP((J) >> 4), 0xF, 0xF, true)); \
    floatx4 u0_ = wb##S##0, u1_ = wb##S##1, u2_ = wb##S##2, u3_ = wb##S##3; \
    if ((J) + 2 < BK) CLOAD((J) + 2, S) \
    vq0 = u0_ * ON + vq0; \
    vq1 = u1_ * ON + vq1; \
    vq2 = u2_ * ON + vq2; \
    vq3 = u3_ * ON + vq3; \
}
#define CSTORE(gidx) \
    if ((lane & 3) == 0) { \
        uint4 pk; \
        pk.x = pack2(o0, o1); pk.y = pack2(o2, o3); \
        pk.z = pack2(o4, o5); pk.w = pack2(o6, o7); \
        *(uint4*)&O[(rr << 11) + ((L0 + (gidx) * 8 + (rr << 3)) & 2047)] = pk; \
        if (k >= 20) { \
            float* op = out + ((long)blockIdx.x * NROWS + rr) * NOUT \
                            + (i0 - OUT_BASE) + (gidx) * 8; \
            *(float4*)op       = float4{o0, o1, o2, o3}; \
            *(float4*)(op + 4) = float4{o4, o5, o6, o7}; \
        } \
    }
#define CINIT(Q) { \
    floatx4 zv_ = *(const floatx4*)(zr + (Q) * 4); \
    float4  bv_ = *(const float4*)(bb + (Q) * 4); \
    vq##Q.x = C5 * (zv_.x + bv_.x); \
    vq##Q.y = C5 * (zv_.y + bv_.y); \
    vq##Q.z = C5 * (zv_.z + bv_.z); \
    vq##Q.w = C5 * (zv_.w + bv_.w); \
}
// 16 steps + 2 stores; slots alternate A/B by step parity (BOF is even)
#define CLEAF(BOF) \
    CSTEP((BOF)+0,0,x,o0,A)  CSTEP((BOF)+1,0,y,o1,B)  CSTEP((BOF)+2,0,z,o2,A)  CSTEP((BOF)+3,0,w,o3,B) \
    CSTEP((BOF)+4,1,x,o4,A)  CSTEP((BOF)+5,1,y,o5,B)  CSTEP((BOF)+6,1,z,o6,A)  CSTEP((BOF)+7,1,w,o7,B) \
    CSTORE((BOF)/8) \
    CSTEP((BOF)+8,2,x,o0,A)  CSTEP((BOF)+9,2,y,o1,B)  CSTEP((BOF)+10,2,z,o2,A) CSTEP((BOF)+11,2,w,o3,B) \
    CSTEP((BOF)+12,3,x,o4,A) CSTEP((BOF)+13,3,y,o5,B) CSTEP((BOF)+14,3,z,o6,A) CSTEP((BOF)+15,3,w,o7,B) \
    CSTORE((BOF)/8 + 1)

__global__ __launch_bounds__(512, 1) void ffnet(const float* __restrict__ x,
                                                const float* __restrict__ W,
                                                const ushort* __restrict__ Wb,
                                                const float* __restrict__ bias,
                                                float* __restrict__ out) {
    __shared__ unsigned short O[NROWS * 2048];   // 64 KB
    __shared__ float Wd[2][64 * WDS];            // 34.8 KB dbuf diag blocks [j][i], C5-scaled
    __shared__ float Zc[NROWS * ZSTR];           // 4.4 KB  [row][node]

    const int t    = threadIdx.x;
    const int w    = t >> 6;        // wave 0..7
    const int lane = t & 63;

    const int cw   = (int)blockIdx.x & 7;
    const int role = (w - cw) & 7;
    const bool isMain   = (role == 1) | (role == 2) | (role == 3) | (role == 5);
    const bool isStager = (role == 4) | (role == 6) | (role == 7);
    const int ng   = (role >= 5) ? 3 : role - 1;              // valid iff isMain
    const int sidx = (role == 4) ? 0 : ((role == 6) ? 1 : 2); // valid iff isStager
    const int spt  = (sidx << 6) + lane;                      // 0..191

    // MFMA frag roles (mains)
    const int m16  = lane & 15;     // A row (batch row) / D col (node in group)
    const int quad = lane >> 4;
    const int arow = m16 << 11;
    const int arot = m16 << 3;

    // chain roles: lane = 4r + g (row r's 4 node-groups in one DPP quad)
    const int rr   = lane >> 2;            // batch row 0..15
    const int g16  = (lane & 3) << 4;      // node-group base (0,16,32,48)

    // ---- stage x rows into LDS as bf16 (swizzled); 8 waves x 2 rows ----
    #pragma unroll
    for (int r2 = 0; r2 < 2; ++r2) {
        const int rs = w + (r2 << 3);
        const long rowS = (long)blockIdx.x * NROWS + rs;
        const float* xr = x + rowS * NIN + lane * 8;
        float4 v0 = *(const float4*)xr;
        float4 v1 = *(const float4*)(xr + 4);
        uint4 pk;
        pk.x = pack2(v0.x, v0.y); pk.y = pack2(v0.z, v0.w);
        pk.z = pack2(v1.x, v1.y); pk.w = pack2(v1.z, v1.w);
        *(uint4*)&O[(rs << 11) + ((lane * 8 + (rs << 3)) & 2047)] = pk;
    }
    __syncthreads();

    short8 tb0 = {}, tb1 = {};      // prefetched tail B-frags
    floatx4 accM = {0.f, 0.f, 0.f, 0.f};

    // ---- prologue (phase-2-like work for slot 0) ----
    if (isMain) {
        const ushort* wbr = Wb + (size_t)((ng << 4) + m16) * NCOLS;
        #pragma unroll 2
        for (int kk = 0; kk < NIN - BK; kk += 32) {
            short8 a = *(const short8*)&O[arow + ((kk + (quad << 3) + arot) & 2047)];
            short8 b = *(const short8*)&wbr[kk + (quad << 3)];
            accM = __builtin_amdgcn_mfma_f32_16x16x32_bf16(a, b, accM, 0, 0, 0);
        }
        tb0 = *(const short8*)&wbr[(NIN - BK) + (quad << 3)];
        tb1 = *(const short8*)&wbr[(NIN - 32) + (quad << 3)];
    } else if (isStager) {
        // stage Wd[0] for block 0: Wd[j*WDS+i] = C5*W[i][512+j]
        const float* wsrc = W + NIN;
        for (int idx = spt; idx < 4096; idx += 192) {
            const int i = idx >> 6, j = idx & 63;
            Wd[0][j * WDS + i] = C5 * wsrc[(size_t)i * NCOLS + j];
        }
    }

    for (int k = 0; k < NBLK; ++k) {
        const int i0 = k << 6;
        const int L0 = NIN + i0;

        // ===== phase 1: mains: tail(k) + Zc^T store =====
        if (isMain) {
            const int ts = L0 - BK;
            short8 a0 = *(const short8*)&O[arow + ((ts + (quad << 3) + arot) & 2047)];
            accM = __builtin_amdgcn_mfma_f32_16x16x32_bf16(a0, tb0, accM, 0, 0, 0);
            short8 a1 = *(const short8*)&O[arow + ((ts + 32 + (quad << 3) + arot) & 2047)];
            accM = __builtin_amdgcn_mfma_f32_16x16x32_bf16(a1, tb1, accM, 0, 0, 0);
            // D: lane q*16+n holds z[row 4q+p][node 16ng+n]
            const int n = (ng << 4) + m16;
            #pragma unroll
            for (int p = 0; p < 4; ++p)
                Zc[((quad << 2) + p) * ZSTR + n] = accM[p];
        }
        __syncthreads();            // beta: Zc(k) + Wd(k) visible

        if (role == 0) {
            // ===== chain: block k, 64 static steps, 2-deep weight pipeline =====
            floatx4 vq0, vq1, vq2, vq3;
            {
                const float* zr = &Zc[rr * ZSTR + g16];
                const float* bb = bias + i0 + g16;
                CINIT(0) CINIT(1) CINIT(2) CINIT(3)
            }
            const float* wd = &Wd[k & 1][0];
            floatx4 wbA0, wbA1, wbA2, wbA3;
            floatx4 wbB0, wbB1, wbB2, wbB3;
            CLOAD(0, A)
            CLOAD(1, B)
            float o0, o1, o2, o3, o4, o5, o6, o7;
            CLEAF(0)
            CLEAF(16)
            CLEAF(32)
            CLEAF(48)
        } else if (isMain && k + 1 < NBLK) {
            // ===== mains: main(k+1) over [0, 512+64k) + tail-B prefetch =====
            const int b = k + 1;
            const ushort* wbr = Wb + (size_t)((b << 6) + (ng << 4) + m16) * NCOLS;
            const int ts = NIN + (b << 6) - BK;
            tb0 = *(const short8*)&wbr[ts + (quad << 3)];
            tb1 = *(const short8*)&wbr[ts + 32 + (quad << 3)];
            floatx4 z = {0.f, 0.f, 0.f, 0.f};
            const int hi = NIN + i0;
            #pragma unroll 2
            for (int kk = 0; kk < hi; kk += 32) {
                short8 a  = *(const short8*)&O[arow + ((kk + (quad << 3) + arot) & 2047)];
                short8 bf = *(const short8*)&wbr[kk + (quad << 3)];
                z = __builtin_amdgcn_mfma_f32_16x16x32_bf16(a, bf, z, 0, 0, 0);
            }
            accM = z;
        } else if (isStager && k + 1 < NBLK) {
            // ===== stagers: Wd[(k+1)&1] = C5 * diag-block(k+1), transposed =====
            const int b = k + 1;
            float* wdn = &Wd[b & 1][0];
            const float* wsrc = W + (size_t)(b << 6) * NCOLS + (NIN + (b << 6));
            for (int idx = spt; idx < 4096; idx += 192) {
                const int i = idx >> 6, j = idx & 63;
                wdn[j * WDS + i] = C5 * wsrc[(size_t)i * NCOLS + j];
            }
        }
        __syncthreads();            // alpha: O(k) visible; Zc/Wd consumed
    }
}

// ---------- launch ----------

extern "C" void kernel_launch(void* const* d_in, const int* in_sizes, int n_in,
                              void* d_out, int out_size, void* d_ws, size_t ws_size,
                              hipStream_t stream) {
    const float* x  = (const float*)d_in[0];   // [4096, 512]
    const float* W  = (const float*)d_in[1];   // [1536, 2048]
    const float* b  = (const float*)d_in[2];   // [1536]
    float* out = (float*)d_out;                // [4096, 256]
    ushort* Wb = (ushort*)d_ws;                // bf16 W copy (6.29 MB, exact proven usage)

    int n8 = NEVAL * NCOLS / 8;
    wconv<<<n8 / 256, 256, 0, stream>>>(W, Wb, n8);
    ffnet<<<4096 / NROWS, 512, 0, stream>>>(x, W, Wb, b, out);
}